// Round 8
// baseline (155.685 us; speedup 1.0000x reference)
//
#include <hip/hip_runtime.h>
#include <hip/hip_bf16.h>

typedef short s16x8 __attribute__((ext_vector_type(8)));
typedef float f32x2 __attribute__((ext_vector_type(2)));
typedef float f32x4 __attribute__((ext_vector_type(4)));
typedef float f32x16 __attribute__((ext_vector_type(16)));
typedef unsigned int u32;
typedef unsigned short u16;
typedef u32 u32x4v __attribute__((ext_vector_type(4)));

#define TOK 216
#define THREADS 448
#define SP 110592           // 48*48*48
#define BUF0 0              // Q stage -> K -> obuf : 224 rows x 256B = 57344
#define VOFF 57344          // Vraw then Vt: 128 ch-rows x 512B = 65536
#define WOFF 122880         // proj_w bf16: 128 rows x 256B = 32768
#define GBOFF 155648        // (old path only) gamma/beta staging
#define LDS_OLD 157696
#define LDS_NEW 155648
#define TENB 28311552ull    // bytes per bf16 tensor copy (110592*128*2)
#define WSNEED (3ull*TENB + 32768ull)

// bf16 pack via builtin casts (RNE); compiler fuses to v_cvt_pk_bf16_f32.
__device__ __forceinline__ u32 pack2(float a, float b) {
  u16 lo = __builtin_bit_cast(u16, __float2bfloat16(a));
  u16 hi = __builtin_bit_cast(u16, __float2bfloat16(b));
  return (u32)lo | ((u32)hi << 16);
}
__device__ __forceinline__ int swz(int row, int inner) {
  return inner ^ ((row & 7) << 4);
}
// async global->LDS, 16B/lane, dest = uniform base + lane*16
__device__ __forceinline__ void gload16(const void* g, void* l) {
  __builtin_amdgcn_global_load_lds(
      (const __attribute__((address_space(1))) void*)g,
      (__attribute__((address_space(3))) void*)l, 16, 0, 0);
}

// per token-pair LN stats over 128 ch held as 32 f32x2 across 4 lanes (old path)
__device__ __forceinline__ void ln_stats(const f32x2* xv, float& mA, float& rA,
                                         float& mB, float& rB) {
  float sA = 0.f, s2A = 0.f, sB = 0.f, s2B = 0.f;
#pragma unroll
  for (int c = 0; c < 32; ++c) {
    sA += xv[c].x; s2A += xv[c].x * xv[c].x;
    sB += xv[c].y; s2B += xv[c].y * xv[c].y;
  }
  sA += __shfl_xor(sA, 1); s2A += __shfl_xor(s2A, 1);
  sB += __shfl_xor(sB, 1); s2B += __shfl_xor(s2B, 1);
  sA += __shfl_xor(sA, 2); s2A += __shfl_xor(s2A, 2);
  sB += __shfl_xor(sB, 2); s2B += __shfl_xor(s2B, 2);
  mA = sA * (1.0f / 128.0f);
  rA = rsqrtf(s2A * (1.0f / 128.0f) - mA * mA + 1e-5f);
  mB = sB * (1.0f / 128.0f);
  rB = rsqrtf(s2B * (1.0f / 128.0f) - mB * mB + 1e-5f);
}

// One (head, k-tile) step. No-max softmax; sigma-permuted V so packed P regs
// are the PV B-fragments directly (verified rounds 6/7).
template<bool MASK>
__device__ __forceinline__ void attn_step(const char* smem, int h, int kt,
                                          s16x8 qfh, int lane,
                                          f32x16& acc, float& lsum) {
  const int half = lane >> 5;
  const int krow = kt * 32 + (lane & 31);
  s16x8 kf = *(const s16x8*)(smem + BUF0 + krow * 256 +
                             swz(krow, h * 32 + half * 16));
  __builtin_amdgcn_s_setprio(1);
  f32x16 st = __builtin_amdgcn_mfma_f32_32x32x16_bf16(kf, qfh, (f32x16){}, 0, 0, 0);
  __builtin_amdgcn_s_setprio(0);
  const int vrow = h * 16 + (lane & 15);
  s16x8 vf0 = *(const s16x8*)(smem + VOFF + vrow * 512 +
                              swz(vrow, kt * 64 + half * 16));
  s16x8 vf1 = *(const s16x8*)(smem + VOFF + vrow * 512 +
                              swz(vrow, kt * 64 + 32 + half * 16));
  const int NR = MASK ? 12 : 16;
  u32 A[8];
  float ts = 0.f;
#pragma unroll
  for (int i = 0; i < 8; ++i) {
    float p0 = (2 * i < NR) ? __expf(st[2 * i]) : 0.f;
    float p1 = (2 * i + 1 < NR) ? __expf(st[2 * i + 1]) : 0.f;
    ts += p0 + p1;
    A[i] = pack2(p0, p1);
  }
  lsum += ts;
  s16x8 pf0 = __builtin_bit_cast(s16x8, (u32x4v){A[0], A[1], A[2], A[3]});
  s16x8 pf1 = __builtin_bit_cast(s16x8, (u32x4v){A[4], A[5], A[6], A[7]});
  __builtin_amdgcn_s_setprio(1);
  acc = __builtin_amdgcn_mfma_f32_32x32x16_bf16(vf0, pf0, acc, 0, 0, 0);
  acc = __builtin_amdgcn_mfma_f32_32x32x16_bf16(vf1, pf1, acc, 0, 0, 0);
  __builtin_amdgcn_s_setprio(0);
}

// ================= Kernel 1: LN + layout transform (new path) ===============
// block (d,h): all 128 ch for 48 w-positions -> complete LN, coalesced both
// sides. block 2304: proj_w fp32 -> bf16.
extern "C" __global__ __launch_bounds__(256)
void lnpre_kernel(const float* __restrict__ qm, const float* __restrict__ km,
                  const float* __restrict__ vm,
                  const float* __restrict__ gq, const float* __restrict__ bq,
                  const float* __restrict__ gkv, const float* __restrict__ bkv,
                  const float* __restrict__ pw,
                  u16* __restrict__ qn, u16* __restrict__ kn,
                  u16* __restrict__ vn, u16* __restrict__ wbf) {
  const int tid = threadIdx.x;
  const int bid = blockIdx.x;
  if (bid >= 2304) {            // W conversion: 16384 f32 -> bf16
#pragma unroll
    for (int k = 0; k < 32; ++k) {
      int idx = tid + 256 * k;
      f32x2 w2 = *(const f32x2*)(pw + idx * 2);
      ((u32*)wbf)[idx] = pack2(w2.x, w2.y);
    }
    return;
  }
  __shared__ float lf[6144];    // [128 ch][48 w] fp32
  __shared__ float gb[512];
  const int d = bid / 48, h = bid - d * 48;
  const int dh = d * 2304 + h * 48;     // global token base of (d,h,0)
  if (tid < 128) {
    gb[tid] = gq[tid]; gb[128 + tid] = bq[tid];
    gb[256 + tid] = gkv[tid]; gb[384 + tid] = bkv[tid];
  }
  const int w = tid >> 2, q = tid & 3;
#pragma unroll 1
  for (int t = 0; t < 3; ++t) {
    const float* src = t == 0 ? qm : (t == 1 ? km : vm);
    u16* dst = t == 0 ? qn : (t == 1 ? kn : vn);
    const float* g = (t == 0) ? gb : gb + 256;
    const float* b = (t == 0) ? gb + 128 : gb + 384;
    const float scale = (t == 0) ? 0.25f : 1.0f;
#pragma unroll
    for (int k = 0; k < 6; ++k) {       // 24KB coalesced load
      int j = tid + 256 * k;
      int ch = j / 12, wq = j - ch * 12;
      *(f32x4*)(lf + ch * 48 + wq * 4) =
          *(const f32x4*)(src + (long)ch * SP + dh + wq * 4);
    }
    __syncthreads();
    if (tid < 192) {                    // thread (w, q): LN of token (d,h,w)
      float s = 0.f, s2 = 0.f;
#pragma unroll
      for (int c = 0; c < 32; ++c) {    // ch = q + 4c: conflict-free cols
        float x = lf[(q + 4 * c) * 48 + w];
        s += x; s2 += x * x;
      }
      s += __shfl_xor(s, 1); s2 += __shfl_xor(s2, 1);
      s += __shfl_xor(s, 2); s2 += __shfl_xor(s2, 2);
      float m = s * (1.f / 128.f);
      float r = rsqrtf(s2 * (1.f / 128.f) - m * m + 1e-5f);
      u32* op = (u32*)(dst + (long)(dh + w) * 128 + 32 * q);
#pragma unroll
      for (int cc = 0; cc < 32; cc += 2) {
        int ch = 32 * q + cc;
        float y0 = ((lf[ch * 48 + w] - m) * r * g[ch] + b[ch]) * scale;
        float y1 = ((lf[(ch + 1) * 48 + w] - m) * r * g[ch + 1] + b[ch + 1]) * scale;
        op[cc >> 1] = pack2(y0, y1);
      }
    }
    __syncthreads();
  }
}

// ================= Kernel 2: attention + projection (new path) ==============
extern "C" __global__ __launch_bounds__(THREADS, 2)
void attn2_kernel(const u16* __restrict__ qn, const u16* __restrict__ kn,
                  const u16* __restrict__ vn, const u16* __restrict__ wbf,
                  const float* __restrict__ pb, float* __restrict__ out) {
  extern __shared__ __align__(16) char smem[];
  const int tid = threadIdx.x;
  const int lane = tid & 63;
  const int wv = tid >> 6;
  const int bid = blockIdx.x;
  const int wid = ((bid & 7) << 6) | (bid >> 3);   // XCD chunked swizzle
  const int wd = wid >> 6, wh = (wid >> 3) & 7, ww = wid & 7;
  const int wd6 = wd * 6, wh6 = wh * 6, ww6 = ww * 6;
  const int boff = wd6 * 2304 + wh6 * 48 + ww6;

  // P1: stage Q (swz-src) -> BUF0, Vraw (linear) -> VOFF, W (swz-src) -> WOFF
  for (int uu = wv; uu < 140; uu += 7) {
    const u16* s; char* d;
    if (uu < 54) {
      int u = uu, row = 4 * u + (lane >> 4);
      int tq = row / 6;
      int g = (wd6 + tq / 6) * 2304 + (wh6 + tq % 6) * 48 + ww6 + row % 6;
      s = qn + g * 128 + (((lane & 15) ^ (row & 7)) << 3);
      d = smem + BUF0 + u * 1024;
    } else if (uu < 108) {
      int u = uu - 54, row = 4 * u + (lane >> 4);
      int tq = row / 6;
      int g = (wd6 + tq / 6) * 2304 + (wh6 + tq % 6) * 48 + ww6 + row % 6;
      s = vn + g * 128 + ((lane & 15) << 3);
      d = smem + VOFF + u * 1024;
    } else {
      int u = uu - 108, row = 4 * u + (lane >> 4);
      s = wbf + row * 128 + (((lane & 15) ^ (row & 7)) << 3);
      d = smem + WOFF + u * 1024;
    }
    gload16(s, d);
  }
  __syncthreads();

  // P2: Q fragments (rows 216-223 stale: NaN-confined to pad-q lanes)
  s16x8 qf[8];
  {
    int row = wv * 32 + (lane & 31);
    int ib = (lane >> 5) * 16;
#pragma unroll
    for (int h = 0; h < 8; ++h)
      qf[h] = *(const s16x8*)(smem + BUF0 + row * 256 + swz(row, h * 32 + ib));
  }
  __syncthreads();

  // P3: stage K -> BUF0 (overwrite Q); read Vraw -> regs
  for (int uu = wv; uu < 54; uu += 7) {
    int row = 4 * uu + (lane >> 4);
    int tq = row / 6;
    int g = (wd6 + tq / 6) * 2304 + (wh6 + tq % 6) * 48 + ww6 + row % 6;
    gload16(kn + g * 128 + (((lane & 15) ^ (row & 7)) << 3),
            smem + BUF0 + uu * 1024);
  }
  u32 tr[32];
#pragma unroll
  for (int k = 0; k < 16; ++k) {
    int u = tid + 448 * k;
    if (u < 6912) {
      int t = (u >> 6) * 2, c2 = u & 63;
      tr[2 * k]     = *(const u32*)(smem + VOFF + t * 256 + c2 * 4);
      tr[2 * k + 1] = *(const u32*)(smem + VOFF + t * 256 + 256 + c2 * 4);
    }
  }
  __syncthreads();

  // P4: write Vt [ch][sigma(tok)] swizzled; zero the read-but-unwritten pads
#pragma unroll
  for (int k = 0; k < 16; ++k) {
    int u = tid + 448 * k;
    if (u < 6912) {
      int t = (u >> 6) * 2, c2 = u & 63;
      int st = (t & ~12) | ((t & 4) << 1) | ((t & 8) >> 1);  // sigma(t), even
      int c = 2 * c2;
      u32 w0 = (tr[2 * k] & 0xFFFFu) | (tr[2 * k + 1] << 16);
      u32 w1 = (tr[2 * k] >> 16) | (tr[2 * k + 1] & 0xFFFF0000u);
      *(u32*)(smem + VOFF + c * 512 + ((st * 2) ^ ((c & 7) << 4))) = w0;
      *(u32*)(smem + VOFF + (c + 1) * 512 + ((st * 2) ^ (((c + 1) & 7) << 4))) = w1;
    }
  }
  if (tid < 128) {   // pad slots: sigma-positions {212-215,220-223}
    int x = (tid & 7) << 4;
    *(u32*)(smem + VOFF + tid * 512 + (424 ^ x)) = 0;
    *(u32*)(smem + VOFF + tid * 512 + (428 ^ x)) = 0;
    *(u32*)(smem + VOFF + tid * 512 + (440 ^ x)) = 0;
    *(u32*)(smem + VOFF + tid * 512 + (444 ^ x)) = 0;
  }
  __syncthreads();

  // P5: attention (verbatim round 7)
  u32 oPk[8][4];
#pragma unroll
  for (int hp = 0; hp < 4; ++hp) {
    const int h0 = hp * 2, h1 = h0 + 1;
    f32x16 a0 = {}, a1 = {};
    float l0 = 0.f, l1 = 0.f;
#pragma unroll 1
    for (int kt = 0; kt < 6; ++kt) {
      attn_step<false>(smem, h0, kt, qf[h0], lane, a0, l0);
      attn_step<false>(smem, h1, kt, qf[h1], lane, a1, l1);
    }
    attn_step<true>(smem, h0, 6, qf[h0], lane, a0, l0);
    attn_step<true>(smem, h1, 6, qf[h1], lane, a1, l1);
    l0 += __shfl_xor(l0, 32);
    l1 += __shfl_xor(l1, 32);
    float i0 = 1.0f / l0, i1 = 1.0f / l1;
#pragma unroll
    for (int r = 0; r < 4; ++r) {
      oPk[h0][r] = pack2(a0[2 * r] * i0, a0[2 * r + 1] * i0);
      oPk[h1][r] = pack2(a1[2 * r] * i1, a1[2 * r + 1] * i1);
    }
  }
  __syncthreads();

  // P6: O^T regs -> obuf (BUF0) [token][ch] bf16
  {
    const int tok = wv * 32 + (lane & 31);
    const int half = lane >> 5;
#pragma unroll
    for (int h = 0; h < 8; ++h) {
      int chb = h * 32 + half * 8;
      *(u32*)(smem + BUF0 + tok * 256 + swz(tok, chb))      = oPk[h][0];
      *(u32*)(smem + BUF0 + tok * 256 + swz(tok, chb + 4))  = oPk[h][1];
      *(u32*)(smem + BUF0 + tok * 256 + swz(tok, chb + 16)) = oPk[h][2];
      *(u32*)(smem + BUF0 + tok * 256 + swz(tok, chb + 20)) = oPk[h][3];
    }
  }
  __syncthreads();

  // P7: projection (verbatim round 7)
#pragma unroll 1
  for (int ti = 0; ti < 2; ++ti) {
    int tt = wv * 2 + ti;
    int tok = tt * 16 + (lane & 15);
    s16x8 bfr[4];
#pragma unroll
    for (int kk = 0; kk < 4; ++kk)
      bfr[kk] = *(const s16x8*)(smem + BUF0 + tok * 256 +
                                swz(tok, kk * 64 + (lane >> 4) * 16));
    bool tokValid = tok < TOK;
    int tdd = tok / 36, trr = tok - tdd * 36;
    int thh = trr / 6, tww = trr - thh * 6;
    int pos = boff + tdd * 2304 + thh * 48 + tww;
#pragma unroll 1
    for (int jt = 0; jt < 8; ++jt) {
      f32x4 acc = {};
#pragma unroll
      for (int kk = 0; kk < 4; ++kk) {
        int rw = jt * 16 + (lane & 15);
        s16x8 af = *(const s16x8*)(smem + WOFF + rw * 256 +
                                   swz(rw, kk * 64 + (lane >> 4) * 16));
        acc = __builtin_amdgcn_mfma_f32_16x16x32_bf16(af, bfr[kk], acc, 0, 0, 0);
      }
      f32x4 pbv = *(const f32x4*)(pb + jt * 16 + (lane >> 4) * 4);
      if (tokValid) {
#pragma unroll
        for (int r = 0; r < 4; ++r) {
          int j = jt * 16 + (lane >> 4) * 4 + r;
          out[j * SP + pos] = acc[r] + pbv[r];
        }
      }
    }
  }
}

// ================= Fallback: round-7 single kernel (verified) ===============
extern "C" __global__ __launch_bounds__(THREADS, 2)
void ca3d_kernel(const float* __restrict__ qm, const float* __restrict__ km,
                 const float* __restrict__ vm,
                 const float* __restrict__ gq, const float* __restrict__ bq,
                 const float* __restrict__ gkv, const float* __restrict__ bkv,
                 const float* __restrict__ pw, const float* __restrict__ pb,
                 float* __restrict__ out) {
  extern __shared__ __align__(16) char smem[];
  const int tid = threadIdx.x;
  const int lane = tid & 63;
  const int wv = tid >> 6;
  const int bid = blockIdx.x;
  const int wid = ((bid & 7) << 6) | (bid >> 3);
  const int wd = wid >> 6, wh = (wid >> 3) & 7, ww = wid & 7;
  const int boff = wd * 6 * 2304 + wh * 6 * 48 + ww * 6;

  for (int i = tid * 16; i < VOFF + 65536; i += THREADS * 16)
    *(f32x4*)(smem + i) = (f32x4){};
  if (tid < 128) {
    ((float*)(smem + GBOFF))[tid] = gq[tid];
    ((float*)(smem + GBOFF + 512))[tid] = bq[tid];
    ((float*)(smem + GBOFF + 1024))[tid] = gkv[tid];
    ((float*)(smem + GBOFF + 1536))[tid] = bkv[tid];
  }
  const bool lnAct = tid < 432;
  const int tp = tid >> 2;
  const int cbase = (tid & 3) * 32;
  const int tA = tp * 2, tB = tA + 1;
  int td = tA / 36, tr_ = tA - td * 36;
  int th_ = tr_ / 6, tw_ = tr_ - th_ * 6;
  const int gpos = boff + td * 2304 + th_ * 48 + tw_;
  const int vposA = (tA & ~0xC) | ((tA & 4) << 1) | ((tA & 8) >> 1);

  f32x2 qv[32], kv[32], vv[32];
  if (lnAct) {
#pragma unroll
    for (int c = 0; c < 32; ++c)
      qv[c] = *(const f32x2*)(qm + gpos + (cbase + c) * SP);
#pragma unroll
    for (int c = 0; c < 32; ++c)
      kv[c] = *(const f32x2*)(km + gpos + (cbase + c) * SP);
  }
  __syncthreads();
  const float* gql = (const float*)(smem + GBOFF);
  const float* bql = (const float*)(smem + GBOFF + 512);
  const float* gkl = (const float*)(smem + GBOFF + 1024);
  const float* bkl = (const float*)(smem + GBOFF + 1536);
  if (lnAct) {
    float mA, rA, mB, rB;
    ln_stats(qv, mA, rA, mB, rB);
#pragma unroll
    for (int c = 0; c < 32; c += 2) {
      int cc = cbase + c;
      float g0 = gql[cc], g1 = gql[cc + 1], b0 = bql[cc], b1 = bql[cc + 1];
      *(u32*)(smem + BUF0 + tA * 256 + swz(tA, cc * 2)) =
          pack2(((qv[c].x - mA) * rA * g0 + b0) * 0.25f,
                ((qv[c + 1].x - mA) * rA * g1 + b1) * 0.25f);
      *(u32*)(smem + BUF0 + tB * 256 + swz(tB, cc * 2)) =
          pack2(((qv[c].y - mB) * rB * g0 + b0) * 0.25f,
                ((qv[c + 1].y - mB) * rB * g1 + b1) * 0.25f);
    }
#pragma unroll
    for (int c = 0; c < 32; ++c)
      vv[c] = *(const f32x2*)(vm + gpos + (cbase + c) * SP);
  }
  __syncthreads();
  s16x8 qf[8];
  {
    int row = wv * 32 + (lane & 31);
    int ib = (lane >> 5) * 16;
#pragma unroll
    for (int h = 0; h < 8; ++h)
      qf[h] = *(const s16x8*)(smem + BUF0 + row * 256 + swz(row, h * 32 + ib));
  }
  __syncthreads();
  if (lnAct) {
    {
      float mA, rA, mB, rB;
      ln_stats(kv, mA, rA, mB, rB);
#pragma unroll
      for (int c = 0; c < 32; c += 2) {
        int cc = cbase + c;
        float g0 = gkl[cc], g1 = gkl[cc + 1], b0 = bkl[cc], b1 = bkl[cc + 1];
        *(u32*)(smem + BUF0 + tA * 256 + swz(tA, cc * 2)) =
            pack2((kv[c].x - mA) * rA * g0 + b0,
                  (kv[c + 1].x - mA) * rA * g1 + b1);
        *(u32*)(smem + BUF0 + tB * 256 + swz(tB, cc * 2)) =
            pack2((kv[c].y - mB) * rB * g0 + b0,
                  (kv[c + 1].y - mB) * rB * g1 + b1);
      }
    }
    {
      float mA, rA, mB, rB;
      ln_stats(vv, mA, rA, mB, rB);
#pragma unroll
      for (int c = 0; c < 32; ++c) {
        int cc = cbase + c;
        float g0 = gkl[cc], b0 = bkl[cc];
        *(u32*)(smem + VOFF + cc * 512 + swz(cc, vposA * 2)) =
            pack2((vv[c].x - mA) * rA * g0 + b0,
                  (vv[c].y - mB) * rB * g0 + b0);
      }
    }
  }
  for (int i = tid; i < 8192; i += THREADS) {
    int j = i >> 6, c2 = i & 63;
    f32x2 w2 = *(const f32x2*)(pw + j * 128 + c2 * 2);
    *(u32*)(smem + WOFF + j * 256 + swz(j, c2 * 4)) = pack2(w2.x, w2.y);
  }
  __syncthreads();
  u32 oPk[8][4];
#pragma unroll
  for (int hp = 0; hp < 4; ++hp) {
    const int h0 = hp * 2, h1 = h0 + 1;
    f32x16 a0 = {}, a1 = {};
    float l0 = 0.f, l1 = 0.f;
#pragma unroll 1
    for (int kt = 0; kt < 6; ++kt) {
      attn_step<false>(smem, h0, kt, qf[h0], lane, a0, l0);
      attn_step<false>(smem, h1, kt, qf[h1], lane, a1, l1);
    }
    attn_step<true>(smem, h0, 6, qf[h0], lane, a0, l0);
    attn_step<true>(smem, h1, 6, qf[h1], lane, a1, l1);
    l0 += __shfl_xor(l0, 32);
    l1 += __shfl_xor(l1, 32);
    float i0 = 1.0f / l0, i1 = 1.0f / l1;
#pragma unroll
    for (int r = 0; r < 4; ++r) {
      oPk[h0][r] = pack2(a0[2 * r] * i0, a0[2 * r + 1] * i0);
      oPk[h1][r] = pack2(a1[2 * r] * i1, a1[2 * r + 1] * i1);
    }
  }
  __syncthreads();
  {
    const int tok = wv * 32 + (lane & 31);
    const int half = lane >> 5;
#pragma unroll
    for (int h = 0; h < 8; ++h) {
      int chb = h * 32 + half * 8;
      *(u32*)(smem + BUF0 + tok * 256 + swz(tok, chb))      = oPk[h][0];
      *(u32*)(smem + BUF0 + tok * 256 + swz(tok, chb + 4))  = oPk[h][1];
      *(u32*)(smem + BUF0 + tok * 256 + swz(tok, chb + 16)) = oPk[h][2];
      *(u32*)(smem + BUF0 + tok * 256 + swz(tok, chb + 20)) = oPk[h][3];
    }
  }
  __syncthreads();
#pragma unroll 1
  for (int ti = 0; ti < 2; ++ti) {
    int tt = wv * 2 + ti;
    int tok = tt * 16 + (lane & 15);
    s16x8 bfr[4];
#pragma unroll
    for (int kk = 0; kk < 4; ++kk)
      bfr[kk] = *(const s16x8*)(smem + BUF0 + tok * 256 +
                                swz(tok, kk * 64 + (lane >> 4) * 16));
    bool tokValid = tok < TOK;
    int tdd = tok / 36, trr = tok - tdd * 36;
    int thh = trr / 6, tww = trr - thh * 6;
    int pos = boff + tdd * 2304 + thh * 48 + tww;
#pragma unroll 1
    for (int jt = 0; jt < 8; ++jt) {
      f32x4 acc = {};
#pragma unroll
      for (int kk = 0; kk < 4; ++kk) {
        int rw = jt * 16 + (lane & 15);
        s16x8 af = *(const s16x8*)(smem + WOFF + rw * 256 +
                                   swz(rw, kk * 64 + (lane >> 4) * 16));
        acc = __builtin_amdgcn_mfma_f32_16x16x32_bf16(af, bfr[kk], acc, 0, 0, 0);
      }
      f32x4 pbv = *(const f32x4*)(pb + jt * 16 + (lane >> 4) * 4);
      if (tokValid) {
#pragma unroll
        for (int r = 0; r < 4; ++r) {
          int j = jt * 16 + (lane >> 4) * 4 + r;
          out[j * SP + pos] = acc[r] + pbv[r];
        }
      }
    }
  }
}

extern "C" void kernel_launch(void* const* d_in, const int* in_sizes, int n_in,
                              void* d_out, int out_size, void* d_ws, size_t ws_size,
                              hipStream_t stream) {
  const float* qm  = (const float*)d_in[0];
  const float* km  = (const float*)d_in[1];
  const float* vm  = (const float*)d_in[2];
  const float* gq  = (const float*)d_in[3];
  const float* bq  = (const float*)d_in[4];
  const float* gkv = (const float*)d_in[5];
  const float* bkv = (const float*)d_in[6];
  const float* pw  = (const float*)d_in[7];
  const float* pb  = (const float*)d_in[8];
  if (ws_size >= WSNEED) {
    u16* qn  = (u16*)d_ws;
    u16* kn  = (u16*)((char*)d_ws + TENB);
    u16* vn  = (u16*)((char*)d_ws + 2 * TENB);
    u16* wbf = (u16*)((char*)d_ws + 3 * TENB);
    hipLaunchKernelGGL(lnpre_kernel, dim3(2305), dim3(256), 0, stream,
                       qm, km, vm, gq, bq, gkv, bkv, pw, qn, kn, vn, wbf);
    hipLaunchKernelGGL(attn2_kernel, dim3(512), dim3(THREADS), LDS_NEW, stream,
                       qn, kn, vn, wbf, pb, (float*)d_out);
  } else {
    hipLaunchKernelGGL(ca3d_kernel, dim3(512), dim3(THREADS), LDS_OLD, stream,
                       qm, km, vm, gq, bq, gkv, bkv, pw, pb, (float*)d_out);
  }
}

// Round 9
// 154.231 us; speedup vs baseline: 1.0094x; 1.0094x over previous
//
#include <hip/hip_runtime.h>
#include <hip/hip_bf16.h>

typedef short s16x8 __attribute__((ext_vector_type(8)));
typedef float f32x2 __attribute__((ext_vector_type(2)));
typedef float f32x4 __attribute__((ext_vector_type(4)));
typedef float f32x16 __attribute__((ext_vector_type(16)));
typedef unsigned int u32;
typedef unsigned short u16;
typedef u32 u32x4v __attribute__((ext_vector_type(4)));

#define TOK 216
#define T1 448              // fallback kernel block
#define T2 896              // attn2 block: 14 waves, 2 head-wavegroups
#define SP 110592           // 48*48*48
#define BUF0 0              // Q stage -> K -> obuf : 224 rows x 256B = 57344
#define VOFF 57344          // Vraw then Vt: 128 ch-rows x 512B = 65536
#define WOFF 122880         // proj_w bf16: 128 rows x 256B = 32768
#define GBOFF 155648        // (old path only) gamma/beta staging
#define LDS_OLD 157696
#define LDS_NEW 155648
#define TENB 28311552ull    // bytes per bf16 tensor copy (110592*128*2)
#define WSNEED (3ull*TENB + 32768ull)
#define QSCALE 0.360673760f // 0.25 * log2(e): QK^T yields scores*log2e -> exp2

// bf16 pack via builtin casts (RNE); compiler fuses to v_cvt_pk_bf16_f32.
__device__ __forceinline__ u32 pack2(float a, float b) {
  u16 lo = __builtin_bit_cast(u16, __float2bfloat16(a));
  u16 hi = __builtin_bit_cast(u16, __float2bfloat16(b));
  return (u32)lo | ((u32)hi << 16);
}
__device__ __forceinline__ int swz(int row, int inner) {
  return inner ^ ((row & 7) << 4);
}
// async global->LDS, 16B/lane, dest = uniform base + lane*16
__device__ __forceinline__ void gload16(const void* g, void* l) {
  __builtin_amdgcn_global_load_lds(
      (const __attribute__((address_space(1))) void*)g,
      (__attribute__((address_space(3))) void*)l, 16, 0, 0);
}

// per token-pair LN stats over 128 ch held as 32 f32x2 across 4 lanes (old path)
__device__ __forceinline__ void ln_stats(const f32x2* xv, float& mA, float& rA,
                                         float& mB, float& rB) {
  float sA = 0.f, s2A = 0.f, sB = 0.f, s2B = 0.f;
#pragma unroll
  for (int c = 0; c < 32; ++c) {
    sA += xv[c].x; s2A += xv[c].x * xv[c].x;
    sB += xv[c].y; s2B += xv[c].y * xv[c].y;
  }
  sA += __shfl_xor(sA, 1); s2A += __shfl_xor(s2A, 1);
  sB += __shfl_xor(sB, 1); s2B += __shfl_xor(s2B, 1);
  sA += __shfl_xor(sA, 2); s2A += __shfl_xor(s2A, 2);
  sB += __shfl_xor(sB, 2); s2B += __shfl_xor(s2B, 2);
  mA = sA * (1.0f / 128.0f);
  rA = rsqrtf(s2A * (1.0f / 128.0f) - mA * mA + 1e-5f);
  mB = sB * (1.0f / 128.0f);
  rB = rsqrtf(s2B * (1.0f / 128.0f) - mB * mB + 1e-5f);
}

// One (head, k-tile) step. No-max softmax with log2e pre-folded into Q
// (QK^T = scores*log2e -> exp2). sigma-permuted V so packed P regs are the
// PV B-fragments directly (verified rounds 6-8).
template<bool MASK>
__device__ __forceinline__ void attn_step(const char* smem, int h, int kt,
                                          s16x8 qfh, int lane,
                                          f32x16& acc, float& lsum) {
  const int half = lane >> 5;
  const int krow = kt * 32 + (lane & 31);
  s16x8 kf = *(const s16x8*)(smem + BUF0 + krow * 256 +
                             swz(krow, h * 32 + half * 16));
  __builtin_amdgcn_s_setprio(1);
  f32x16 st = __builtin_amdgcn_mfma_f32_32x32x16_bf16(kf, qfh, (f32x16){}, 0, 0, 0);
  __builtin_amdgcn_s_setprio(0);
  const int vrow = h * 16 + (lane & 15);
  s16x8 vf0 = *(const s16x8*)(smem + VOFF + vrow * 512 +
                              swz(vrow, kt * 64 + half * 16));
  s16x8 vf1 = *(const s16x8*)(smem + VOFF + vrow * 512 +
                              swz(vrow, kt * 64 + 32 + half * 16));
  const int NR = MASK ? 12 : 16;
  u32 A[8];
  float ts0 = 0.f, ts1 = 0.f;
#pragma unroll
  for (int i = 0; i < 8; ++i) {
    float p0 = (2 * i < NR) ? __builtin_amdgcn_exp2f(st[2 * i]) : 0.f;
    float p1 = (2 * i + 1 < NR) ? __builtin_amdgcn_exp2f(st[2 * i + 1]) : 0.f;
    if (i & 1) ts1 += p0 + p1; else ts0 += p0 + p1;
    A[i] = pack2(p0, p1);
  }
  lsum += ts0 + ts1;
  s16x8 pf0 = __builtin_bit_cast(s16x8, (u32x4v){A[0], A[1], A[2], A[3]});
  s16x8 pf1 = __builtin_bit_cast(s16x8, (u32x4v){A[4], A[5], A[6], A[7]});
  __builtin_amdgcn_s_setprio(1);
  acc = __builtin_amdgcn_mfma_f32_32x32x16_bf16(vf0, pf0, acc, 0, 0, 0);
  acc = __builtin_amdgcn_mfma_f32_32x32x16_bf16(vf1, pf1, acc, 0, 0, 0);
  __builtin_amdgcn_s_setprio(0);
}

// ================= Kernel 1: LN + layout transform (new path) ===============
extern "C" __global__ __launch_bounds__(256)
void lnpre_kernel(const float* __restrict__ qm, const float* __restrict__ km,
                  const float* __restrict__ vm,
                  const float* __restrict__ gq, const float* __restrict__ bq,
                  const float* __restrict__ gkv, const float* __restrict__ bkv,
                  const float* __restrict__ pw,
                  u16* __restrict__ qn, u16* __restrict__ kn,
                  u16* __restrict__ vn, u16* __restrict__ wbf) {
  const int tid = threadIdx.x;
  const int bid = blockIdx.x;
  if (bid >= 2304) {            // W conversion: 16384 f32 -> bf16
#pragma unroll
    for (int k = 0; k < 32; ++k) {
      int idx = tid + 256 * k;
      f32x2 w2 = *(const f32x2*)(pw + idx * 2);
      ((u32*)wbf)[idx] = pack2(w2.x, w2.y);
    }
    return;
  }
  __shared__ float lf[6144];    // [128 ch][48 w] fp32
  __shared__ float gb[512];
  const int d = bid / 48, h = bid - d * 48;
  const int dh = d * 2304 + h * 48;     // global token base of (d,h,0)
  if (tid < 128) {
    gb[tid] = gq[tid]; gb[128 + tid] = bq[tid];
    gb[256 + tid] = gkv[tid]; gb[384 + tid] = bkv[tid];
  }
  const int w = tid >> 2, q = tid & 3;
#pragma unroll 1
  for (int t = 0; t < 3; ++t) {
    const float* src = t == 0 ? qm : (t == 1 ? km : vm);
    u16* dst = t == 0 ? qn : (t == 1 ? kn : vn);
    const float* g = (t == 0) ? gb : gb + 256;
    const float* b = (t == 0) ? gb + 128 : gb + 384;
    const float scale = (t == 0) ? QSCALE : 1.0f;
#pragma unroll
    for (int k = 0; k < 6; ++k) {       // 24KB coalesced load
      int j = tid + 256 * k;
      int ch = j / 12, wq = j - ch * 12;
      *(f32x4*)(lf + ch * 48 + wq * 4) =
          *(const f32x4*)(src + (long)ch * SP + dh + wq * 4);
    }
    __syncthreads();
    if (tid < 192) {                    // thread (w, q): LN of token (d,h,w)
      float s = 0.f, s2 = 0.f;
#pragma unroll
      for (int c = 0; c < 32; ++c) {
        float x = lf[(q + 4 * c) * 48 + w];
        s += x; s2 += x * x;
      }
      s += __shfl_xor(s, 1); s2 += __shfl_xor(s2, 1);
      s += __shfl_xor(s, 2); s2 += __shfl_xor(s2, 2);
      float m = s * (1.f / 128.f);
      float r = rsqrtf(s2 * (1.f / 128.f) - m * m + 1e-5f);
      u32x4v* op = (u32x4v*)(dst + (long)(dh + w) * 128 + 32 * q);
#pragma unroll
      for (int v4 = 0; v4 < 4; ++v4) {
        u32x4v pk;
#pragma unroll
        for (int e = 0; e < 4; ++e) {
          int ch = 32 * q + v4 * 8 + 2 * e;
          float y0 = ((lf[ch * 48 + w] - m) * r * g[ch] + b[ch]) * scale;
          float y1 = ((lf[(ch + 1) * 48 + w] - m) * r * g[ch + 1] + b[ch + 1]) * scale;
          pk[e] = pack2(y0, y1);
        }
        op[v4] = pk;
      }
    }
    __syncthreads();
  }
}

// ================= Kernel 2: attention + projection (new path) ==============
// 14 waves: waves 0-6 = heads 0-3, waves 7-13 = heads 4-7 (same q rows,
// disjoint output columns). Doubles waves/SIMD (1.75 -> 3.5) for latency hiding.
extern "C" __global__ __launch_bounds__(T2, 1)
void attn2_kernel(const u16* __restrict__ qn, const u16* __restrict__ kn,
                  const u16* __restrict__ vn, const u16* __restrict__ wbf,
                  const float* __restrict__ pb, float* __restrict__ out) {
  extern __shared__ __align__(16) char smem[];
  const int tid = threadIdx.x;
  const int lane = tid & 63;
  const int wv = tid >> 6;          // 0..13
  const int wq = wv % 7;            // q-row group
  const int hb = (wv / 7) * 4;      // head base for this wavegroup
  const int bid = blockIdx.x;
  const int wid = ((bid & 7) << 6) | (bid >> 3);   // XCD chunked swizzle
  const int wd = wid >> 6, wh = (wid >> 3) & 7, ww = wid & 7;
  const int wd6 = wd * 6, wh6 = wh * 6, ww6 = ww * 6;
  const int boff = wd6 * 2304 + wh6 * 48 + ww6;

  // P1: stage Q (swz-src) -> BUF0, Vraw (linear) -> VOFF, W (swz-src) -> WOFF
  for (int uu = wv; uu < 140; uu += 14) {
    const u16* s; char* d;
    if (uu < 54) {
      int u = uu, row = 4 * u + (lane >> 4);
      int tq = row / 6;
      int g = (wd6 + tq / 6) * 2304 + (wh6 + tq % 6) * 48 + ww6 + row % 6;
      s = qn + g * 128 + (((lane & 15) ^ (row & 7)) << 3);
      d = smem + BUF0 + u * 1024;
    } else if (uu < 108) {
      int u = uu - 54, row = 4 * u + (lane >> 4);
      int tq = row / 6;
      int g = (wd6 + tq / 6) * 2304 + (wh6 + tq % 6) * 48 + ww6 + row % 6;
      s = vn + g * 128 + ((lane & 15) << 3);
      d = smem + VOFF + u * 1024;
    } else {
      int u = uu - 108, row = 4 * u + (lane >> 4);
      s = wbf + row * 128 + (((lane & 15) ^ (row & 7)) << 3);
      d = smem + WOFF + u * 1024;
    }
    gload16(s, d);
  }
  __syncthreads();

  // P2: Q fragments for this wavegroup's 4 heads
  s16x8 qf[4];
  {
    int row = wq * 32 + (lane & 31);
    int ib = (lane >> 5) * 16;
#pragma unroll
    for (int j = 0; j < 4; ++j)
      qf[j] = *(const s16x8*)(smem + BUF0 + row * 256 +
                              swz(row, (hb + j) * 32 + ib));
  }
  __syncthreads();

  // P3: stage K -> BUF0 (overwrite Q); read Vraw -> regs
  for (int uu = wv; uu < 54; uu += 14) {
    int row = 4 * uu + (lane >> 4);
    int tq = row / 6;
    int g = (wd6 + tq / 6) * 2304 + (wh6 + tq % 6) * 48 + ww6 + row % 6;
    gload16(kn + g * 128 + (((lane & 15) ^ (row & 7)) << 3),
            smem + BUF0 + uu * 1024);
  }
  u32 tr[16];
#pragma unroll
  for (int k = 0; k < 8; ++k) {
    int u = tid + 896 * k;
    if (u < 6912) {
      int t = (u >> 6) * 2, c2 = u & 63;
      tr[2 * k]     = *(const u32*)(smem + VOFF + t * 256 + c2 * 4);
      tr[2 * k + 1] = *(const u32*)(smem + VOFF + t * 256 + 256 + c2 * 4);
    }
  }
  __syncthreads();

  // P4: write Vt [ch][sigma(tok)] swizzled; zero the read-but-unwritten pads
#pragma unroll
  for (int k = 0; k < 8; ++k) {
    int u = tid + 896 * k;
    if (u < 6912) {
      int t = (u >> 6) * 2, c2 = u & 63;
      int st = (t & ~12) | ((t & 4) << 1) | ((t & 8) >> 1);  // sigma(t), even
      int c = 2 * c2;
      u32 w0 = (tr[2 * k] & 0xFFFFu) | (tr[2 * k + 1] << 16);
      u32 w1 = (tr[2 * k] >> 16) | (tr[2 * k + 1] & 0xFFFF0000u);
      *(u32*)(smem + VOFF + c * 512 + ((st * 2) ^ ((c & 7) << 4))) = w0;
      *(u32*)(smem + VOFF + (c + 1) * 512 + ((st * 2) ^ (((c + 1) & 7) << 4))) = w1;
    }
  }
  if (tid < 128) {   // pad slots: sigma-positions {212-215,220-223}
    int x = (tid & 7) << 4;
    *(u32*)(smem + VOFF + tid * 512 + (424 ^ x)) = 0;
    *(u32*)(smem + VOFF + tid * 512 + (428 ^ x)) = 0;
    *(u32*)(smem + VOFF + tid * 512 + (440 ^ x)) = 0;
    *(u32*)(smem + VOFF + tid * 512 + (444 ^ x)) = 0;
  }
  __syncthreads();

  // P5: attention -- 2 head-pairs per wave
  u32 oPk[4][4];
#pragma unroll
  for (int hp = 0; hp < 2; ++hp) {
    const int h0 = hb + 2 * hp, h1 = h0 + 1;
    f32x16 a0 = {}, a1 = {};
    float l0 = 0.f, l1 = 0.f;
#pragma unroll 2
    for (int kt = 0; kt < 6; ++kt) {
      attn_step<false>(smem, h0, kt, qf[2 * hp], lane, a0, l0);
      attn_step<false>(smem, h1, kt, qf[2 * hp + 1], lane, a1, l1);
    }
    attn_step<true>(smem, h0, 6, qf[2 * hp], lane, a0, l0);
    attn_step<true>(smem, h1, 6, qf[2 * hp + 1], lane, a1, l1);
    l0 += __shfl_xor(l0, 32);
    l1 += __shfl_xor(l1, 32);
    float i0 = 1.0f / l0, i1 = 1.0f / l1;
#pragma unroll
    for (int r = 0; r < 4; ++r) {
      oPk[2 * hp][r]     = pack2(a0[2 * r] * i0, a0[2 * r + 1] * i0);
      oPk[2 * hp + 1][r] = pack2(a1[2 * r] * i1, a1[2 * r + 1] * i1);
    }
  }
  __syncthreads();

  // P6: O^T regs -> obuf (BUF0) [token][ch] bf16 (wavegroups: disjoint bytes)
  {
    const int tok = wq * 32 + (lane & 31);
    const int half = lane >> 5;
#pragma unroll
    for (int j = 0; j < 4; ++j) {
      int chb = (hb + j) * 32 + half * 8;
      *(u32*)(smem + BUF0 + tok * 256 + swz(tok, chb))      = oPk[j][0];
      *(u32*)(smem + BUF0 + tok * 256 + swz(tok, chb + 4))  = oPk[j][1];
      *(u32*)(smem + BUF0 + tok * 256 + swz(tok, chb + 16)) = oPk[j][2];
      *(u32*)(smem + BUF0 + tok * 256 + swz(tok, chb + 20)) = oPk[j][3];
    }
  }
  __syncthreads();

  // P7: projection: D[j][token] = W(A) x O(B); wave owns 1 token tile
  {
    int tok = wv * 16 + (lane & 15);
    s16x8 bfr[4];
#pragma unroll
    for (int kk = 0; kk < 4; ++kk)
      bfr[kk] = *(const s16x8*)(smem + BUF0 + tok * 256 +
                                swz(tok, kk * 64 + (lane >> 4) * 16));
    bool tokValid = tok < TOK;
    int tdd = tok / 36, trr = tok - tdd * 36;
    int thh = trr / 6, tww = trr - thh * 6;
    int pos = boff + tdd * 2304 + thh * 48 + tww;
#pragma unroll 1
    for (int jt = 0; jt < 8; ++jt) {
      f32x4 acc = {};
#pragma unroll
      for (int kk = 0; kk < 4; ++kk) {
        int rw = jt * 16 + (lane & 15);
        s16x8 af = *(const s16x8*)(smem + WOFF + rw * 256 +
                                   swz(rw, kk * 64 + (lane >> 4) * 16));
        acc = __builtin_amdgcn_mfma_f32_16x16x32_bf16(af, bfr[kk], acc, 0, 0, 0);
      }
      f32x4 pbv = *(const f32x4*)(pb + jt * 16 + (lane >> 4) * 4);
      if (tokValid) {
#pragma unroll
        for (int r = 0; r < 4; ++r) {
          int j = jt * 16 + (lane >> 4) * 4 + r;
          out[j * SP + pos] = acc[r] + pbv[r];
        }
      }
    }
  }
}

// ================= Fallback: single kernel (round-7 structure) ==============
extern "C" __global__ __launch_bounds__(T1, 2)
void ca3d_kernel(const float* __restrict__ qm, const float* __restrict__ km,
                 const float* __restrict__ vm,
                 const float* __restrict__ gq, const float* __restrict__ bq,
                 const float* __restrict__ gkv, const float* __restrict__ bkv,
                 const float* __restrict__ pw, const float* __restrict__ pb,
                 float* __restrict__ out) {
  extern __shared__ __align__(16) char smem[];
  const int tid = threadIdx.x;
  const int lane = tid & 63;
  const int wv = tid >> 6;
  const int bid = blockIdx.x;
  const int wid = ((bid & 7) << 6) | (bid >> 3);
  const int wd = wid >> 6, wh = (wid >> 3) & 7, ww = wid & 7;
  const int boff = wd * 6 * 2304 + wh * 6 * 48 + ww * 6;

  for (int i = tid * 16; i < VOFF + 65536; i += T1 * 16)
    *(f32x4*)(smem + i) = (f32x4){};
  if (tid < 128) {
    ((float*)(smem + GBOFF))[tid] = gq[tid];
    ((float*)(smem + GBOFF + 512))[tid] = bq[tid];
    ((float*)(smem + GBOFF + 1024))[tid] = gkv[tid];
    ((float*)(smem + GBOFF + 1536))[tid] = bkv[tid];
  }
  const bool lnAct = tid < 432;
  const int tp = tid >> 2;
  const int cbase = (tid & 3) * 32;
  const int tA = tp * 2, tB = tA + 1;
  int td = tA / 36, tr_ = tA - td * 36;
  int th_ = tr_ / 6, tw_ = tr_ - th_ * 6;
  const int gpos = boff + td * 2304 + th_ * 48 + tw_;
  const int vposA = (tA & ~0xC) | ((tA & 4) << 1) | ((tA & 8) >> 1);

  f32x2 qv[32], kv[32], vv[32];
  if (lnAct) {
#pragma unroll
    for (int c = 0; c < 32; ++c)
      qv[c] = *(const f32x2*)(qm + gpos + (cbase + c) * SP);
#pragma unroll
    for (int c = 0; c < 32; ++c)
      kv[c] = *(const f32x2*)(km + gpos + (cbase + c) * SP);
  }
  __syncthreads();
  const float* gql = (const float*)(smem + GBOFF);
  const float* bql = (const float*)(smem + GBOFF + 512);
  const float* gkl = (const float*)(smem + GBOFF + 1024);
  const float* bkl = (const float*)(smem + GBOFF + 1536);
  if (lnAct) {
    float mA, rA, mB, rB;
    ln_stats(qv, mA, rA, mB, rB);
#pragma unroll
    for (int c = 0; c < 32; c += 2) {
      int cc = cbase + c;
      float g0 = gql[cc], g1 = gql[cc + 1], b0 = bql[cc], b1 = bql[cc + 1];
      *(u32*)(smem + BUF0 + tA * 256 + swz(tA, cc * 2)) =
          pack2(((qv[c].x - mA) * rA * g0 + b0) * QSCALE,
                ((qv[c + 1].x - mA) * rA * g1 + b1) * QSCALE);
      *(u32*)(smem + BUF0 + tB * 256 + swz(tB, cc * 2)) =
          pack2(((qv[c].y - mB) * rB * g0 + b0) * QSCALE,
                ((qv[c + 1].y - mB) * rB * g1 + b1) * QSCALE);
    }
#pragma unroll
    for (int c = 0; c < 32; ++c)
      vv[c] = *(const f32x2*)(vm + gpos + (cbase + c) * SP);
  }
  __syncthreads();
  s16x8 qf[8];
  {
    int row = wv * 32 + (lane & 31);
    int ib = (lane >> 5) * 16;
#pragma unroll
    for (int h = 0; h < 8; ++h)
      qf[h] = *(const s16x8*)(smem + BUF0 + row * 256 + swz(row, h * 32 + ib));
  }
  __syncthreads();
  if (lnAct) {
    {
      float mA, rA, mB, rB;
      ln_stats(kv, mA, rA, mB, rB);
#pragma unroll
      for (int c = 0; c < 32; c += 2) {
        int cc = cbase + c;
        float g0 = gkl[cc], g1 = gkl[cc + 1], b0 = bkl[cc], b1 = bkl[cc + 1];
        *(u32*)(smem + BUF0 + tA * 256 + swz(tA, cc * 2)) =
            pack2((kv[c].x - mA) * rA * g0 + b0,
                  (kv[c + 1].x - mA) * rA * g1 + b1);
        *(u32*)(smem + BUF0 + tB * 256 + swz(tB, cc * 2)) =
            pack2((kv[c].y - mB) * rB * g0 + b0,
                  (kv[c + 1].y - mB) * rB * g1 + b1);
      }
    }
    {
      float mA, rA, mB, rB;
      ln_stats(vv, mA, rA, mB, rB);
#pragma unroll
      for (int c = 0; c < 32; ++c) {
        int cc = cbase + c;
        float g0 = gkl[cc], b0 = bkl[cc];
        *(u32*)(smem + VOFF + cc * 512 + swz(cc, vposA * 2)) =
            pack2((vv[c].x - mA) * rA * g0 + b0,
                  (vv[c].y - mB) * rB * g0 + b0);
      }
    }
  }
  for (int i = tid; i < 8192; i += T1) {
    int j = i >> 6, c2 = i & 63;
    f32x2 w2 = *(const f32x2*)(pw + j * 128 + c2 * 2);
    *(u32*)(smem + WOFF + j * 256 + swz(j, c2 * 4)) = pack2(w2.x, w2.y);
  }
  __syncthreads();
  u32 oPk[8][4];
#pragma unroll
  for (int hp = 0; hp < 4; ++hp) {
    const int h0 = hp * 2, h1 = h0 + 1;
    f32x16 a0 = {}, a1 = {};
    float l0 = 0.f, l1 = 0.f;
#pragma unroll 1
    for (int kt = 0; kt < 6; ++kt) {
      attn_step<false>(smem, h0, kt, qf[h0], lane, a0, l0);
      attn_step<false>(smem, h1, kt, qf[h1], lane, a1, l1);
    }
    attn_step<true>(smem, h0, 6, qf[h0], lane, a0, l0);
    attn_step<true>(smem, h1, 6, qf[h1], lane, a1, l1);
    l0 += __shfl_xor(l0, 32);
    l1 += __shfl_xor(l1, 32);
    float i0 = 1.0f / l0, i1 = 1.0f / l1;
#pragma unroll
    for (int r = 0; r < 4; ++r) {
      oPk[h0][r] = pack2(a0[2 * r] * i0, a0[2 * r + 1] * i0);
      oPk[h1][r] = pack2(a1[2 * r] * i1, a1[2 * r + 1] * i1);
    }
  }
  __syncthreads();
  {
    const int tok = wv * 32 + (lane & 31);
    const int half = lane >> 5;
#pragma unroll
    for (int h = 0; h < 8; ++h) {
      int chb = h * 32 + half * 8;
      *(u32*)(smem + BUF0 + tok * 256 + swz(tok, chb))      = oPk[h][0];
      *(u32*)(smem + BUF0 + tok * 256 + swz(tok, chb + 4))  = oPk[h][1];
      *(u32*)(smem + BUF0 + tok * 256 + swz(tok, chb + 16)) = oPk[h][2];
      *(u32*)(smem + BUF0 + tok * 256 + swz(tok, chb + 20)) = oPk[h][3];
    }
  }
  __syncthreads();
#pragma unroll 1
  for (int ti = 0; ti < 2; ++ti) {
    int tt = wv * 2 + ti;
    int tok = tt * 16 + (lane & 15);
    s16x8 bfr[4];
#pragma unroll
    for (int kk = 0; kk < 4; ++kk)
      bfr[kk] = *(const s16x8*)(smem + BUF0 + tok * 256 +
                                swz(tok, kk * 64 + (lane >> 4) * 16));
    bool tokValid = tok < TOK;
    int tdd = tok / 36, trr = tok - tdd * 36;
    int thh = trr / 6, tww = trr - thh * 6;
    int pos = boff + tdd * 2304 + thh * 48 + tww;
#pragma unroll 1
    for (int jt = 0; jt < 8; ++jt) {
      f32x4 acc = {};
#pragma unroll
      for (int kk = 0; kk < 4; ++kk) {
        int rw = jt * 16 + (lane & 15);
        s16x8 af = *(const s16x8*)(smem + WOFF + rw * 256 +
                                   swz(rw, kk * 64 + (lane >> 4) * 16));
        acc = __builtin_amdgcn_mfma_f32_16x16x32_bf16(af, bfr[kk], acc, 0, 0, 0);
      }
      f32x4 pbv = *(const f32x4*)(pb + jt * 16 + (lane >> 4) * 4);
      if (tokValid) {
#pragma unroll
        for (int r = 0; r < 4; ++r) {
          int j = jt * 16 + (lane >> 4) * 4 + r;
          out[j * SP + pos] = acc[r] + pbv[r];
        }
      }
    }
  }
}

extern "C" void kernel_launch(void* const* d_in, const int* in_sizes, int n_in,
                              void* d_out, int out_size, void* d_ws, size_t ws_size,
                              hipStream_t stream) {
  const float* qm  = (const float*)d_in[0];
  const float* km  = (const float*)d_in[1];
  const float* vm  = (const float*)d_in[2];
  const float* gq  = (const float*)d_in[3];
  const float* bq  = (const float*)d_in[4];
  const float* gkv = (const float*)d_in[5];
  const float* bkv = (const float*)d_in[6];
  const float* pw  = (const float*)d_in[7];
  const float* pb  = (const float*)d_in[8];
  if (ws_size >= WSNEED) {
    u16* qn  = (u16*)d_ws;
    u16* kn  = (u16*)((char*)d_ws + TENB);
    u16* vn  = (u16*)((char*)d_ws + 2 * TENB);
    u16* wbf = (u16*)((char*)d_ws + 3 * TENB);
    hipLaunchKernelGGL(lnpre_kernel, dim3(2305), dim3(256), 0, stream,
                       qm, km, vm, gq, bq, gkv, bkv, pw, qn, kn, vn, wbf);
    hipLaunchKernelGGL(attn2_kernel, dim3(512), dim3(T2), LDS_NEW, stream,
                       qn, kn, vn, wbf, pb, (float*)d_out);
  } else {
    hipLaunchKernelGGL(ca3d_kernel, dim3(512), dim3(T1), LDS_OLD, stream,
                       qm, km, vm, gq, bq, gkv, bkv, pw, pb, (float*)d_out);
  }
}